// Round 17
// baseline (131.802 us; speedup 1.0000x reference)
//
#include <hip/hip_runtime.h>
#include <hip/hip_bf16.h>
#include <math.h>

// Problem constants (fixed by reference)
#define SEQ   3072
#define EMB   1280
#define NHEAD 16
#define HDIM  80
#define QKVN  3840   // 3*EMB
#define NSEGS 3

typedef __attribute__((ext_vector_type(8))) short bf16x8;  // 8 bf16 (4 VGPRs)
typedef __attribute__((ext_vector_type(4))) short bf16x4;  // 4 bf16 (8 B)
typedef __attribute__((ext_vector_type(4))) float f32x4;   // MFMA C/D frag

__device__ __forceinline__ short f2bf(float f) {
    __hip_bfloat16 h = __float2bfloat16(f);
    return *reinterpret_cast<short*>(&h);
}
__device__ __forceinline__ float bf2f(short s) {
    unsigned int u = ((unsigned int)(unsigned short)s) << 16;
    union { unsigned int u; float f; } c; c.u = u;
    return c.f;
}

// async global->LDS, 16 B per lane; LDS dest = wave-uniform base + lane*16
__device__ __forceinline__ void gload_lds16(const void* g, void* l) {
    __builtin_amdgcn_global_load_lds(
        (const __attribute__((address_space(1))) unsigned int*)g,
        (__attribute__((address_space(3))) unsigned int*)l, 16, 0, 0);
}

// ---------------------------------------------------------------------------
// f32 -> bf16 conversion for all three inputs in ONE launch (8 elems/thread)
// ---------------------------------------------------------------------------
__global__ __launch_bounds__(256)
void cvt3_kernel(const float* __restrict__ a, short* __restrict__ oa, int na8,
                 const float* __restrict__ b, short* __restrict__ ob, int nb8,
                 const float* __restrict__ c, short* __restrict__ oc, int nc8)
{
    int j = blockIdx.x * 256 + threadIdx.x;
    const float* src; short* dst;
    if (j < na8) { src = a; dst = oa; }
    else if ((j -= na8) < nb8) { src = b; dst = ob; }
    else { j -= nb8; src = c; dst = oc; }
    float4 x = *reinterpret_cast<const float4*>(&src[j*8]);
    float4 y = *reinterpret_cast<const float4*>(&src[j*8+4]);
    bf16x8 o;
    o[0]=f2bf(x.x); o[1]=f2bf(x.y); o[2]=f2bf(x.z); o[3]=f2bf(x.w);
    o[4]=f2bf(y.x); o[5]=f2bf(y.y); o[6]=f2bf(y.z); o[7]=f2bf(y.w);
    *reinterpret_cast<bf16x8*>(&dst[j*8]) = o;
}

// ---------------------------------------------------------------------------
// bf16 MFMA GEMM, 128x128 tile, BK=32, 2-phase double-buffer (verified r16).
// SWZ: XCD-aware 1-D grid decode (verified round 15; bijective, rows=8*3).
// ---------------------------------------------------------------------------
__device__ __forceinline__ void store_val(float v, float* p) { *p = v; }
__device__ __forceinline__ void store_val(float v, short* p) { *p = f2bf(v); }

template<typename OT, bool SWZ>
__global__ __launch_bounds__(256)
void gemm_bf16_nt(const short* __restrict__ A, int lda,
                  const short* __restrict__ B,
                  const float* __restrict__ bias, OT* __restrict__ C,
                  int M, int N, int K)
{
    __shared__ short As0[128][32], Bs0[128][32];   // buffer 0 (16 KB)
    __shared__ short As1[128][32], Bs1[128][32];   // buffer 1 (16 KB)

    int bx, by;
    if (SWZ) {
        const int flat = blockIdx.x;
        const int xcd  = flat & 7;
        const int i    = flat >> 3;
        by = xcd * 3 + (i % 3);
        bx = i / 3;
    } else {
        bx = blockIdx.x;
        by = blockIdx.y;
    }

    const int tid = threadIdx.x;
    const int w   = tid >> 6;
    const int l   = tid & 63;
    const int l15 = l & 15;
    const int l4  = l >> 4;
    const int wr  = w >> 1;
    const int wc  = w & 1;
    const int row0 = by * 128;
    const int col0 = bx * 128;

    const int srow = l >> 2;
    const int sk   = (l & 3) * 8;
    const int c0 = w, c1 = w + 4;

    f32x4 acc[4][4];
    #pragma unroll
    for (int mi = 0; mi < 4; ++mi)
        #pragma unroll
        for (int ni = 0; ni < 4; ++ni) acc[mi][ni] = (f32x4){0.f,0.f,0.f,0.f};

#define STAGE_NT(AS, BS, KOFF)                                                          \
    do {                                                                                \
        gload_lds16(&A[(size_t)(row0 + c0*16 + srow) * lda + (KOFF) + sk], &AS[c0*16][0]); \
        gload_lds16(&A[(size_t)(row0 + c1*16 + srow) * lda + (KOFF) + sk], &AS[c1*16][0]); \
        gload_lds16(&B[(size_t)(col0 + c0*16 + srow) * K   + (KOFF) + sk], &BS[c0*16][0]); \
        gload_lds16(&B[(size_t)(col0 + c1*16 + srow) * K   + (KOFF) + sk], &BS[c1*16][0]); \
    } while (0)

#define COMPUTE_NT(AS, BS)                                                              \
    do {                                                                                \
        bf16x8 af[4], bfr[4];                                                           \
        _Pragma("unroll")                                                               \
        for (int mi = 0; mi < 4; ++mi)                                                  \
            af[mi] = *reinterpret_cast<const bf16x8*>(&AS[wr*64 + mi*16 + l15][l4*8]);  \
        _Pragma("unroll")                                                               \
        for (int ni = 0; ni < 4; ++ni)                                                  \
            bfr[ni] = *reinterpret_cast<const bf16x8*>(&BS[wc*64 + ni*16 + l15][l4*8]); \
        _Pragma("unroll")                                                               \
        for (int mi = 0; mi < 4; ++mi)                                                  \
            _Pragma("unroll")                                                           \
            for (int ni = 0; ni < 4; ++ni)                                              \
                acc[mi][ni] = __builtin_amdgcn_mfma_f32_16x16x32_bf16(                  \
                    af[mi], bfr[ni], acc[mi][ni], 0, 0, 0);                             \
    } while (0)

    STAGE_NT(As0, Bs0, 0);
    __syncthreads();

    for (int k0 = 0; k0 < K; k0 += 64) {
        if (k0 + 32 < K) STAGE_NT(As1, Bs1, k0 + 32);
        COMPUTE_NT(As0, Bs0);
        __syncthreads();
        if (k0 + 64 < K) STAGE_NT(As0, Bs0, k0 + 64);
        COMPUTE_NT(As1, Bs1);
        __syncthreads();
    }
#undef STAGE_NT
#undef COMPUTE_NT

    #pragma unroll
    for (int ni = 0; ni < 4; ++ni) {
        int col = col0 + wc*64 + ni*16 + l15;
        float bv = bias[col];
        #pragma unroll
        for (int mi = 0; mi < 4; ++mi) {
            #pragma unroll
            for (int r = 0; r < 4; ++r) {
                size_t row = (size_t)(row0 + wr*64 + mi*16 + l4*4 + r);
                store_val(acc[mi][ni][r] + bv, &C[row * (size_t)N + col]);
            }
        }
    }
}

// ---------------------------------------------------------------------------
// bf16 MFMA GEMM, 128x64 tile, BK=32, 2-phase double-buffer — proj GEMM.
// ---------------------------------------------------------------------------
template<typename OT>
__global__ __launch_bounds__(256)
void gemm_bf16_nt64(const short* __restrict__ A, int lda,
                    const short* __restrict__ B,
                    const float* __restrict__ bias, OT* __restrict__ C,
                    int M, int N, int K)
{
    __shared__ short As0[128][32], Bs0[64][32];   // buffer 0 (12 KB)
    __shared__ short As1[128][32], Bs1[64][32];   // buffer 1 (12 KB)

    const int tid = threadIdx.x;
    const int w   = tid >> 6;
    const int l   = tid & 63;
    const int l15 = l & 15;
    const int l4  = l >> 4;
    const int wr  = w >> 1;
    const int wc  = w & 1;
    const int row0 = blockIdx.y * 128;
    const int col0 = blockIdx.x * 64;

    const int srow = l >> 2;
    const int sk   = (l & 3) * 8;
    const int c0 = w, c1 = w + 4;

    f32x4 acc[4][2];
    #pragma unroll
    for (int mi = 0; mi < 4; ++mi)
        #pragma unroll
        for (int ni = 0; ni < 2; ++ni) acc[mi][ni] = (f32x4){0.f,0.f,0.f,0.f};

#define STAGE_NT64(AS, BS, KOFF)                                                        \
    do {                                                                                \
        gload_lds16(&A[(size_t)(row0 + c0*16 + srow) * lda + (KOFF) + sk], &AS[c0*16][0]); \
        gload_lds16(&A[(size_t)(row0 + c1*16 + srow) * lda + (KOFF) + sk], &AS[c1*16][0]); \
        gload_lds16(&B[(size_t)(col0 + w*16  + srow) * K   + (KOFF) + sk], &BS[w*16][0]);  \
    } while (0)

#define COMPUTE_NT64(AS, BS)                                                            \
    do {                                                                                \
        bf16x8 af[4], bfr[2];                                                           \
        _Pragma("unroll")                                                               \
        for (int mi = 0; mi < 4; ++mi)                                                  \
            af[mi] = *reinterpret_cast<const bf16x8*>(&AS[wr*64 + mi*16 + l15][l4*8]);  \
        _Pragma("unroll")                                                               \
        for (int ni = 0; ni < 2; ++ni)                                                  \
            bfr[ni] = *reinterpret_cast<const bf16x8*>(&BS[wc*32 + ni*16 + l15][l4*8]); \
        _Pragma("unroll")                                                               \
        for (int mi = 0; mi < 4; ++mi)                                                  \
            _Pragma("unroll")                                                           \
            for (int ni = 0; ni < 2; ++ni)                                              \
                acc[mi][ni] = __builtin_amdgcn_mfma_f32_16x16x32_bf16(                  \
                    af[mi], bfr[ni], acc[mi][ni], 0, 0, 0);                             \
    } while (0)

    STAGE_NT64(As0, Bs0, 0);
    __syncthreads();

    for (int k0 = 0; k0 < K; k0 += 64) {
        if (k0 + 32 < K) STAGE_NT64(As1, Bs1, k0 + 32);
        COMPUTE_NT64(As0, Bs0);
        __syncthreads();
        if (k0 + 64 < K) STAGE_NT64(As0, Bs0, k0 + 64);
        COMPUTE_NT64(As1, Bs1);
        __syncthreads();
    }
#undef STAGE_NT64
#undef COMPUTE_NT64

    #pragma unroll
    for (int ni = 0; ni < 2; ++ni) {
        int col = col0 + wc*32 + ni*16 + l15;
        float bv = bias[col];
        #pragma unroll
        for (int mi = 0; mi < 4; ++mi) {
            #pragma unroll
            for (int r = 0; r < 4; ++r) {
                size_t row = (size_t)(row0 + wr*64 + mi*16 + l4*4 + r);
                store_val(acc[mi][ni][r] + bv, &C[row * (size_t)N + col]);
            }
        }
    }
}

// ---------------------------------------------------------------------------
// RoPE in-place on bf16 q,k slices (unchanged).
// ---------------------------------------------------------------------------
__global__ __launch_bounds__(256)
void rope_bf16_kernel(short* __restrict__ qkv, const float* __restrict__ rpe)
{
    int idx = blockIdx.x * 256 + threadIdx.x;
    int blk = idx % 5;
    int h   = (idx / 5) % NHEAD;
    int s   = (idx / (5*NHEAD)) % SEQ;
    int t   = idx / (5*NHEAD*SEQ);
    int d0  = blk * 8;

    const float* rp = rpe + s*40 + d0;
    short* p = qkv + (size_t)s*QKVN + t*EMB + h*HDIM + d0;
    bf16x8 v0 = *reinterpret_cast<const bf16x8*>(p);
    bf16x8 v1 = *reinterpret_cast<const bf16x8*>(p + 40);
    bf16x8 o0, o1;
    #pragma unroll
    for (int j = 0; j < 8; ++j) {
        float ang = rp[j];
        float sn = sinf(ang), cs = cosf(ang);
        float a = bf2f(v0[j]), b = bf2f(v1[j]);
        o0[j] = f2bf(a*cs - b*sn);
        o1[j] = f2bf(b*cs + a*sn);
    }
    *reinterpret_cast<bf16x8*>(p)      = o0;
    *reinterpret_cast<bf16x8*>(p + 40) = o1;
}

// ---------------------------------------------------------------------------
// MFMA flash attention — round 12/16 verified algebra, now with DOUBLE-
// BUFFERED K/V LDS and ONE barrier per chunk (round 17):
//   per chunk: {ds-write chunk t+1 into buf^1 (overlaps MFMA pipe) ->
//   issue chunk t+2 global loads -> compute chunk t from buf -> barrier}.
//   WAR safe: buf^1 was last READ in chunk t-1, whose end-barrier ordered
//   those reads before this chunk's writes. LDS 26.6 -> 53.2 KB: grid gives
//   only 3 blocks/CU and 3 x 52 KB = 156 KB <= 160 KB -> zero occupancy cost.
// Layout per buffer (shorts): K tile [64][128] at +0, V^T tile at +8192.
// ---------------------------------------------------------------------------
#define ABUF 13312   // shorts per buffer: 8192 (K) + 5120 (V^T)

__global__ __launch_bounds__(256, 4)
void attn_mfma(const short* __restrict__ qkv, const int* __restrict__ cu,
               short* __restrict__ aout)
{
    const int flat = blockIdx.x;
    const int xcd  = flat & 7;
    const int rem  = flat >> 3;
    const int qt   = rem & 15;
    const int shhi = rem >> 4;
    const int sh   = xcd + 8*shhi;    // 0..47
    const int h    = sh / 3;
    const int seg  = sh - 3*h;
    const int s0 = cu[seg], s1 = cu[seg+1];

    const int tid = threadIdx.x;
    const int w   = tid >> 6;
    const int l   = tid & 63;
    const int l15 = l & 15;
    const int l4  = l >> 4;

    __shared__ short lds[2 * ABUF];   // 53248 B total

    const int q0 = s0 + qt*64 + w*16;

    bf16x8 bzero;
    #pragma unroll
    for (int j = 0; j < 8; ++j) bzero[j] = 0;

    // Q fragments (B-operand): col=l15=qrow, k=l4*8+j = d (padded 80->96)
    bf16x8 qf[3];
    {
        const short* qp = qkv + (size_t)(q0 + l15) * QKVN + h*HDIM;
        qf[0] = *reinterpret_cast<const bf16x8*>(qp + l4*8);
        qf[1] = *reinterpret_cast<const bf16x8*>(qp + 32 + l4*8);
        qf[2] = (l4 < 2) ? *reinterpret_cast<const bf16x8*>(qp + 64 + l4*8) : bzero;
    }

    // per-lane softmax state (exp2 domain, scaled), q-row = q0 + l15
    float m = -3.4e38f, lsum = 0.f;
    f32x4 O[5];   // O^T: lane holds d = dt*16 + 4*l4 + r, qrow = l15
    #pragma unroll
    for (int dt = 0; dt < 5; ++dt) O[dt] = (f32x4){0.f,0.f,0.f,0.f};

    // ---- K staging geometry (LDS offsets within a buffer) ----
    int ku[3], kofs[3];
    const short* kptr[3];
    #pragma unroll
    for (int i = 0; i < 3; ++i) {
        int task = tid + i*256;
        int key  = task / 12;
        ku[i]    = task - key*12;
        kptr[i]  = qkv + (size_t)(s0 + key)*QKVN + EMB + h*HDIM + ku[i]*8;
        kofs[i]  = key*128 + (ku[i] ^ (key & 7))*8;
    }

    // ---- V staging geometry (uniform): key k=l, d in [20w, 20w+20) ----
    const int vu  = ((l >> 2) & 3) | ((l >> 5) << 2);   // unit 0..7
    const int vbs = ((l >> 4) & 1) * 4 + (l & 3);       // pos  0..7
    const int vd0 = w * 20;
    const short* vp1 = qkv + (size_t)(s0 + l) * QKVN + 2*EMB + h*HDIM + vd0;

    const float scale2 = 0.1612982054f;   // log2(e)/sqrt(80)
    const int nk = s1 - s0;
    const size_t step = (size_t)64 * QKVN;

    // ---- staged registers ----
    bf16x8 kreg[3];
    bf16x8 vA, vB;
    bf16x4 vC;

#define LOAD_REGS()                                                             \
    do {                                                                        \
        _Pragma("unroll")                                                       \
        for (int i = 0; i < 3; ++i)                                             \
            if (ku[i] < 10) kreg[i] = *reinterpret_cast<const bf16x8*>(kptr[i]);\
        vA = *reinterpret_cast<const bf16x8*>(vp1);                             \
        vB = *reinterpret_cast<const bf16x8*>(vp1 + 8);                         \
        vC = *reinterpret_cast<const bf16x4*>(vp1 + 16);                        \
    } while (0)

#define WRITE_LDS(OFF)                                                          \
    do {                                                                        \
        short* kb = &lds[(OFF)];                                                \
        short* vb = &lds[(OFF) + 8192];                                         \
        _Pragma("unroll")                                                       \
        for (int i = 0; i < 3; ++i)                                             \
            *reinterpret_cast<bf16x8*>(&kb[kofs[i]]) = kreg[i];                 \
        _Pragma("unroll")                                                       \
        for (int e = 0; e < 8; ++e) {                                           \
            int d = vd0 + e;                                                    \
            vb[d*64 + ((vu ^ (d & 7)) & 7)*8 + vbs] = vA[e];                    \
        }                                                                       \
        _Pragma("unroll")                                                       \
        for (int e = 0; e < 8; ++e) {                                           \
            int d = vd0 + 8 + e;                                                \
            vb[d*64 + ((vu ^ (d & 7)) & 7)*8 + vbs] = vB[e];                    \
        }                                                                       \
        _Pragma("unroll")                                                       \
        for (int e = 0; e < 4; ++e) {                                           \
            int d = vd0 + 16 + e;                                               \
            vb[d*64 + ((vu ^ (d & 7)) & 7)*8 + vbs] = vC[e];                    \
        }                                                                       \
    } while (0)

    #pragma unroll
    for (int i = 0; i < 3; ++i) kreg[i] = bzero;   // pad units stay zero

    // ---- prologue: chunk 0 -> buf 0; prefetch chunk 1 regs ----
    LOAD_REGS();
    WRITE_LDS(0);
    if (nk > 64) {
        #pragma unroll
        for (int i = 0; i < 3; ++i) kptr[i] += step;
        vp1 += step;
        LOAD_REGS();
    }
    __syncthreads();

    int curoff = 0;
    for (int kc = 0; kc < nk; kc += 64) {
        // stage chunk t+1 into the other buffer (overlaps with compute below)
        if (kc + 64 < nk) {
            WRITE_LDS(curoff ^ ABUF);
            if (kc + 128 < nk) {
                #pragma unroll
                for (int i = 0; i < 3; ++i) kptr[i] += step;
                vp1 += step;
                LOAD_REGS();
            }
        }

        const short* kb = &lds[curoff];
        const short* vb = &lds[curoff + 8192];

        // ---- S^T = K Q : 4 key-tiles x 3 k-steps (swapped operands) ----
        f32x4 S[4];
        __builtin_amdgcn_s_setprio(1);
        #pragma unroll
        for (int ct = 0; ct < 4; ++ct) {
            f32x4 acc = (f32x4){0.f,0.f,0.f,0.f};
            int key = ct*16 + l15;
            #pragma unroll
            for (int t = 0; t < 3; ++t) {
                int u = (4*t + l4) ^ (key & 7);
                bf16x8 a = *reinterpret_cast<const bf16x8*>(&kb[key*128 + u*8]);
                acc = __builtin_amdgcn_mfma_f32_16x16x32_bf16(a, qf[t], acc, 0, 0, 0);
            }
            S[ct] = acc;   // S[ct][r] = S^T[key=16ct+4*l4+r][qrow=l15]
        }
        __builtin_amdgcn_s_setprio(0);

        // ---- per-lane online softmax over 64 keys (max on raw S) ----
        float mxr = -3.4e38f;
        #pragma unroll
        for (int ct = 0; ct < 4; ++ct)
            #pragma unroll
            for (int r = 0; r < 4; ++r) mxr = fmaxf(mxr, S[ct][r]);
        float mx = mxr * scale2;
        mx = fmaxf(mx, __shfl_xor(mx, 16));
        mx = fmaxf(mx, __shfl_xor(mx, 32));
        // T13 defer-rescale: skip O-rescale when bounded (P <= 2^8, f32 acc)
        if (!__all(mx - m <= 8.f)) {
            float mn   = fmaxf(m, mx);
            float corr = exp2f(m - mn);
            lsum *= corr;
            #pragma unroll
            for (int dt = 0; dt < 5; ++dt)
                #pragma unroll
                for (int r = 0; r < 4; ++r) O[dt][r] *= corr;
            m = mn;
        }
        float p[4][4];
        float ps = 0.f;
        #pragma unroll
        for (int ct = 0; ct < 4; ++ct)
            #pragma unroll
            for (int r = 0; r < 4; ++r) {
                float e = exp2f(fmaf(S[ct][r], scale2, -m));
                p[ct][r] = e;
                ps += e;
            }
        ps += __shfl_xor(ps, 16);
        ps += __shfl_xor(ps, 32);
        lsum += ps;

        // ---- O^T += V^T P^T : per s-half one b128 A-frag read per d-tile ----
        #pragma unroll
        for (int s2 = 0; s2 < 2; ++s2) {
            bf16x8 pb;
            #pragma unroll
            for (int j = 0; j < 8; ++j)
                pb[j] = f2bf(p[2*s2 + (j>>2)][j & 3]);
            __builtin_amdgcn_s_setprio(1);
            #pragma unroll
            for (int dt = 0; dt < 5; ++dt) {
                int d = dt*16 + l15;
                bf16x8 va = *reinterpret_cast<const bf16x8*>(
                    &vb[d*64 + (((4*s2 + l4) ^ (d & 7)) & 7)*8]);
                O[dt] = __builtin_amdgcn_mfma_f32_16x16x32_bf16(va, pb, O[dt], 0, 0, 0);
            }
            __builtin_amdgcn_s_setprio(0);
        }

        __syncthreads();   // one barrier per chunk: buf^1 writes visible,
        curoff ^= ABUF;    // buf reads complete (WAR for next iteration)
    }
#undef LOAD_REGS
#undef WRITE_LDS

    // ---- normalize (per-lane scalar), write O^T as packed 8 B stores ----
    float inv = 1.f / lsum;
    short* orow = aout + (size_t)(q0 + l15) * EMB + h*HDIM;
    #pragma unroll
    for (int dt = 0; dt < 5; ++dt) {
        bf16x4 o4;
        #pragma unroll
        for (int r = 0; r < 4; ++r) o4[r] = f2bf(O[dt][r] * inv);
        *reinterpret_cast<bf16x4*>(&orow[dt*16 + 4*l4]) = o4;
    }
}

// ---------------------------------------------------------------------------
extern "C" void kernel_launch(void* const* d_in, const int* in_sizes, int n_in,
                              void* d_out, int out_size, void* d_ws, size_t ws_size,
                              hipStream_t stream)
{
    const float* x      = (const float*)d_in[0];
    const float* rpe    = (const float*)d_in[1];
    const float* qkv_w  = (const float*)d_in[2];
    const float* qkv_b  = (const float*)d_in[3];
    const float* proj_w = (const float*)d_in[4];
    const float* proj_b = (const float*)d_in[5];
    const int*   cu     = (const int*)d_in[6];
    float* out = (float*)d_out;

    short* ws       = (short*)d_ws;
    short* qkv_bf   = ws;                                   // SEQ*QKVN
    short* x_bf     = qkv_bf  + (size_t)SEQ * QKVN;         // SEQ*EMB
    short* qkvw_bf  = x_bf    + (size_t)SEQ * EMB;          // QKVN*EMB
    short* projw_bf = qkvw_bf + (size_t)QKVN * EMB;         // EMB*EMB
    short* attn_bf  = projw_bf+ (size_t)EMB * EMB;          // SEQ*EMB

    dim3 blk(256);

    // 0) convert all three inputs to bf16 in one launch
    const int na8 = SEQ*EMB/8, nb8 = QKVN*EMB/8, nc8 = EMB*EMB/8;
    cvt3_kernel<<<dim3((na8+nb8+nc8)/256), blk, 0, stream>>>(
        x, x_bf, na8, qkv_w, qkvw_bf, nb8, proj_w, projw_bf, nc8);

    // 1) qkv = x @ qkv_w^T + qkv_b  (bf16 out; 128x128 tile, XCD-swizzled
    //    1-D grid, 2-phase double-buffered K-loop)
    gemm_bf16_nt<short, true><<<dim3((QKVN/128)*(SEQ/128)), blk, 0, stream>>>(
        x_bf, EMB, qkvw_bf, qkv_b, qkv_bf, SEQ, QKVN, EMB);

    // 2) RoPE in-place on bf16 q,k
    rope_bf16_kernel<<<dim3(2*SEQ*NHEAD*5/256), blk, 0, stream>>>(qkv_bf, rpe);

    // 3) block-diagonal MFMA attention -> bf16 planar attn_bf
    //    (1-D XCD grid, double-buffered K/V, one barrier per chunk)
    attn_mfma<<<dim3(16*NSEGS*NHEAD), blk, 0, stream>>>(qkv_bf, cu, attn_bf);

    // 4) out = attn @ proj_w^T + proj_b (f32 out, 128x64 tile, dbuf)
    gemm_bf16_nt64<float><<<dim3(EMB/64, SEQ/128), blk, 0, stream>>>(
        attn_bf, EMB, projw_bf, proj_b, out, SEQ, EMB, EMB);
}

// Round 18
// 127.850 us; speedup vs baseline: 1.0309x; 1.0309x over previous
//
#include <hip/hip_runtime.h>
#include <hip/hip_bf16.h>
#include <math.h>

// Problem constants (fixed by reference)
#define SEQ   3072
#define EMB   1280
#define NHEAD 16
#define HDIM  80
#define QKVN  3840   // 3*EMB
#define NSEGS 3

typedef __attribute__((ext_vector_type(8))) short bf16x8;  // 8 bf16 (4 VGPRs)
typedef __attribute__((ext_vector_type(4))) short bf16x4;  // 4 bf16 (8 B)
typedef __attribute__((ext_vector_type(4))) float f32x4;   // MFMA C/D frag

__device__ __forceinline__ short f2bf(float f) {
    __hip_bfloat16 h = __float2bfloat16(f);
    return *reinterpret_cast<short*>(&h);
}
__device__ __forceinline__ float bf2f(short s) {
    unsigned int u = ((unsigned int)(unsigned short)s) << 16;
    union { unsigned int u; float f; } c; c.u = u;
    return c.f;
}

// async global->LDS, 16 B per lane; LDS dest = wave-uniform base + lane*16
__device__ __forceinline__ void gload_lds16(const void* g, void* l) {
    __builtin_amdgcn_global_load_lds(
        (const __attribute__((address_space(1))) unsigned int*)g,
        (__attribute__((address_space(3))) unsigned int*)l, 16, 0, 0);
}

// ---------------------------------------------------------------------------
// f32 -> bf16 conversion for all three inputs in ONE launch (8 elems/thread)
// ---------------------------------------------------------------------------
__global__ __launch_bounds__(256)
void cvt3_kernel(const float* __restrict__ a, short* __restrict__ oa, int na8,
                 const float* __restrict__ b, short* __restrict__ ob, int nb8,
                 const float* __restrict__ c, short* __restrict__ oc, int nc8)
{
    int j = blockIdx.x * 256 + threadIdx.x;
    const float* src; short* dst;
    if (j < na8) { src = a; dst = oa; }
    else if ((j -= na8) < nb8) { src = b; dst = ob; }
    else { j -= nb8; src = c; dst = oc; }
    float4 x = *reinterpret_cast<const float4*>(&src[j*8]);
    float4 y = *reinterpret_cast<const float4*>(&src[j*8+4]);
    bf16x8 o;
    o[0]=f2bf(x.x); o[1]=f2bf(x.y); o[2]=f2bf(x.z); o[3]=f2bf(x.w);
    o[4]=f2bf(y.x); o[5]=f2bf(y.y); o[6]=f2bf(y.z); o[7]=f2bf(y.w);
    *reinterpret_cast<bf16x8*>(&dst[j*8]) = o;
}

// ---------------------------------------------------------------------------
// bf16 MFMA GEMM, 128x128 tile, BK=32, 2-phase double-buffer (verified r16).
// SWZ: XCD-aware 1-D grid decode (verified round 15; bijective, rows=8*3).
// ---------------------------------------------------------------------------
__device__ __forceinline__ void store_val(float v, float* p) { *p = v; }
__device__ __forceinline__ void store_val(float v, short* p) { *p = f2bf(v); }

template<typename OT, bool SWZ>
__global__ __launch_bounds__(256)
void gemm_bf16_nt(const short* __restrict__ A, int lda,
                  const short* __restrict__ B,
                  const float* __restrict__ bias, OT* __restrict__ C,
                  int M, int N, int K)
{
    __shared__ short As0[128][32], Bs0[128][32];   // buffer 0 (16 KB)
    __shared__ short As1[128][32], Bs1[128][32];   // buffer 1 (16 KB)

    int bx, by;
    if (SWZ) {
        const int flat = blockIdx.x;
        const int xcd  = flat & 7;
        const int i    = flat >> 3;
        by = xcd * 3 + (i % 3);
        bx = i / 3;
    } else {
        bx = blockIdx.x;
        by = blockIdx.y;
    }

    const int tid = threadIdx.x;
    const int w   = tid >> 6;
    const int l   = tid & 63;
    const int l15 = l & 15;
    const int l4  = l >> 4;
    const int wr  = w >> 1;
    const int wc  = w & 1;
    const int row0 = by * 128;
    const int col0 = bx * 128;

    const int srow = l >> 2;
    const int sk   = (l & 3) * 8;
    const int c0 = w, c1 = w + 4;

    f32x4 acc[4][4];
    #pragma unroll
    for (int mi = 0; mi < 4; ++mi)
        #pragma unroll
        for (int ni = 0; ni < 4; ++ni) acc[mi][ni] = (f32x4){0.f,0.f,0.f,0.f};

#define STAGE_NT(AS, BS, KOFF)                                                          \
    do {                                                                                \
        gload_lds16(&A[(size_t)(row0 + c0*16 + srow) * lda + (KOFF) + sk], &AS[c0*16][0]); \
        gload_lds16(&A[(size_t)(row0 + c1*16 + srow) * lda + (KOFF) + sk], &AS[c1*16][0]); \
        gload_lds16(&B[(size_t)(col0 + c0*16 + srow) * K   + (KOFF) + sk], &BS[c0*16][0]); \
        gload_lds16(&B[(size_t)(col0 + c1*16 + srow) * K   + (KOFF) + sk], &BS[c1*16][0]); \
    } while (0)

#define COMPUTE_NT(AS, BS)                                                              \
    do {                                                                                \
        bf16x8 af[4], bfr[4];                                                           \
        _Pragma("unroll")                                                               \
        for (int mi = 0; mi < 4; ++mi)                                                  \
            af[mi] = *reinterpret_cast<const bf16x8*>(&AS[wr*64 + mi*16 + l15][l4*8]);  \
        _Pragma("unroll")                                                               \
        for (int ni = 0; ni < 4; ++ni)                                                  \
            bfr[ni] = *reinterpret_cast<const bf16x8*>(&BS[wc*64 + ni*16 + l15][l4*8]); \
        _Pragma("unroll")                                                               \
        for (int mi = 0; mi < 4; ++mi)                                                  \
            _Pragma("unroll")                                                           \
            for (int ni = 0; ni < 4; ++ni)                                              \
                acc[mi][ni] = __builtin_amdgcn_mfma_f32_16x16x32_bf16(                  \
                    af[mi], bfr[ni], acc[mi][ni], 0, 0, 0);                             \
    } while (0)

    STAGE_NT(As0, Bs0, 0);
    __syncthreads();

    for (int k0 = 0; k0 < K; k0 += 64) {
        if (k0 + 32 < K) STAGE_NT(As1, Bs1, k0 + 32);
        COMPUTE_NT(As0, Bs0);
        __syncthreads();
        if (k0 + 64 < K) STAGE_NT(As0, Bs0, k0 + 64);
        COMPUTE_NT(As1, Bs1);
        __syncthreads();
    }
#undef STAGE_NT
#undef COMPUTE_NT

    #pragma unroll
    for (int ni = 0; ni < 4; ++ni) {
        int col = col0 + wc*64 + ni*16 + l15;
        float bv = bias[col];
        #pragma unroll
        for (int mi = 0; mi < 4; ++mi) {
            #pragma unroll
            for (int r = 0; r < 4; ++r) {
                size_t row = (size_t)(row0 + wr*64 + mi*16 + l4*4 + r);
                store_val(acc[mi][ni][r] + bv, &C[row * (size_t)N + col]);
            }
        }
    }
}

// ---------------------------------------------------------------------------
// bf16 MFMA GEMM, 128x64 tile, BK=32, 2-phase double-buffer — proj GEMM.
// SWZ (round 18): XCD-aware 1-D decode, 480 blocks = 8 XCDs x (20 cols x 3
// rows); bijective for M/128 = 24 = 8*3. Pure block remap, bit-identical.
// ---------------------------------------------------------------------------
template<typename OT, bool SWZ>
__global__ __launch_bounds__(256)
void gemm_bf16_nt64(const short* __restrict__ A, int lda,
                    const short* __restrict__ B,
                    const float* __restrict__ bias, OT* __restrict__ C,
                    int M, int N, int K)
{
    __shared__ short As0[128][32], Bs0[64][32];   // buffer 0 (12 KB)
    __shared__ short As1[128][32], Bs1[64][32];   // buffer 1 (12 KB)

    int bx, by;
    if (SWZ) {
        const int flat = blockIdx.x;
        const int xcd  = flat & 7;
        const int i    = flat >> 3;
        by = xcd * 3 + (i % 3);
        bx = i / 3;
    } else {
        bx = blockIdx.x;
        by = blockIdx.y;
    }

    const int tid = threadIdx.x;
    const int w   = tid >> 6;
    const int l   = tid & 63;
    const int l15 = l & 15;
    const int l4  = l >> 4;
    const int wr  = w >> 1;
    const int wc  = w & 1;
    const int row0 = by * 128;
    const int col0 = bx * 64;

    const int srow = l >> 2;
    const int sk   = (l & 3) * 8;
    const int c0 = w, c1 = w + 4;

    f32x4 acc[4][2];
    #pragma unroll
    for (int mi = 0; mi < 4; ++mi)
        #pragma unroll
        for (int ni = 0; ni < 2; ++ni) acc[mi][ni] = (f32x4){0.f,0.f,0.f,0.f};

#define STAGE_NT64(AS, BS, KOFF)                                                        \
    do {                                                                                \
        gload_lds16(&A[(size_t)(row0 + c0*16 + srow) * lda + (KOFF) + sk], &AS[c0*16][0]); \
        gload_lds16(&A[(size_t)(row0 + c1*16 + srow) * lda + (KOFF) + sk], &AS[c1*16][0]); \
        gload_lds16(&B[(size_t)(col0 + w*16  + srow) * K   + (KOFF) + sk], &BS[w*16][0]);  \
    } while (0)

#define COMPUTE_NT64(AS, BS)                                                            \
    do {                                                                                \
        bf16x8 af[4], bfr[2];                                                           \
        _Pragma("unroll")                                                               \
        for (int mi = 0; mi < 4; ++mi)                                                  \
            af[mi] = *reinterpret_cast<const bf16x8*>(&AS[wr*64 + mi*16 + l15][l4*8]);  \
        _Pragma("unroll")                                                               \
        for (int ni = 0; ni < 2; ++ni)                                                  \
            bfr[ni] = *reinterpret_cast<const bf16x8*>(&BS[wc*32 + ni*16 + l15][l4*8]); \
        _Pragma("unroll")                                                               \
        for (int mi = 0; mi < 4; ++mi)                                                  \
            _Pragma("unroll")                                                           \
            for (int ni = 0; ni < 2; ++ni)                                              \
                acc[mi][ni] = __builtin_amdgcn_mfma_f32_16x16x32_bf16(                  \
                    af[mi], bfr[ni], acc[mi][ni], 0, 0, 0);                             \
    } while (0)

    STAGE_NT64(As0, Bs0, 0);
    __syncthreads();

    for (int k0 = 0; k0 < K; k0 += 64) {
        if (k0 + 32 < K) STAGE_NT64(As1, Bs1, k0 + 32);
        COMPUTE_NT64(As0, Bs0);
        __syncthreads();
        if (k0 + 64 < K) STAGE_NT64(As0, Bs0, k0 + 64);
        COMPUTE_NT64(As1, Bs1);
        __syncthreads();
    }
#undef STAGE_NT64
#undef COMPUTE_NT64

    #pragma unroll
    for (int ni = 0; ni < 2; ++ni) {
        int col = col0 + wc*32 + ni*16 + l15;
        float bv = bias[col];
        #pragma unroll
        for (int mi = 0; mi < 4; ++mi) {
            #pragma unroll
            for (int r = 0; r < 4; ++r) {
                size_t row = (size_t)(row0 + wr*64 + mi*16 + l4*4 + r);
                store_val(acc[mi][ni][r] + bv, &C[row * (size_t)N + col]);
            }
        }
    }
}

// ---------------------------------------------------------------------------
// RoPE in-place on bf16 q,k slices (unchanged).
// ---------------------------------------------------------------------------
__global__ __launch_bounds__(256)
void rope_bf16_kernel(short* __restrict__ qkv, const float* __restrict__ rpe)
{
    int idx = blockIdx.x * 256 + threadIdx.x;
    int blk = idx % 5;
    int h   = (idx / 5) % NHEAD;
    int s   = (idx / (5*NHEAD)) % SEQ;
    int t   = idx / (5*NHEAD*SEQ);
    int d0  = blk * 8;

    const float* rp = rpe + s*40 + d0;
    short* p = qkv + (size_t)s*QKVN + t*EMB + h*HDIM + d0;
    bf16x8 v0 = *reinterpret_cast<const bf16x8*>(p);
    bf16x8 v1 = *reinterpret_cast<const bf16x8*>(p + 40);
    bf16x8 o0, o1;
    #pragma unroll
    for (int j = 0; j < 8; ++j) {
        float ang = rp[j];
        float sn = sinf(ang), cs = cosf(ang);
        float a = bf2f(v0[j]), b = bf2f(v1[j]);
        o0[j] = f2bf(a*cs - b*sn);
        o1[j] = f2bf(b*cs + a*sn);
    }
    *reinterpret_cast<bf16x8*>(p)      = o0;
    *reinterpret_cast<bf16x8*>(p + 40) = o1;
}

// ---------------------------------------------------------------------------
// MFMA flash attention — round 16 verified structure (REVERTED from r17's
// double-buffer, which regressed: VGPR 64->80 + ds_write/ds_read LDS-pipe
// contention during compute). KC=64, swapped QK^T, per-lane softmax, T13
// defer-rescale, XCD decode, uniform V staging, __launch_bounds__(256,4).
// ---------------------------------------------------------------------------
__global__ __launch_bounds__(256, 4)
void attn_mfma(const short* __restrict__ qkv, const int* __restrict__ cu,
               short* __restrict__ aout)
{
    const int flat = blockIdx.x;
    const int xcd  = flat & 7;
    const int rem  = flat >> 3;
    const int qt   = rem & 15;
    const int shhi = rem >> 4;
    const int sh   = xcd + 8*shhi;    // 0..47
    const int h    = sh / 3;
    const int seg  = sh - 3*h;
    const int s0 = cu[seg], s1 = cu[seg+1];

    const int tid = threadIdx.x;
    const int w   = tid >> 6;
    const int l   = tid & 63;
    const int l15 = l & 15;
    const int l4  = l >> 4;

    __shared__ short Kl[64][128];    // 16 KB: K rows, XOR-swizzled 8-elem units
    __shared__ short Vt[HDIM][64];   // 10 KB: V^T, quad-permuted + swizzled

    const int q0 = s0 + qt*64 + w*16;

    bf16x8 bzero;
    #pragma unroll
    for (int j = 0; j < 8; ++j) bzero[j] = 0;

    // Q fragments (B-operand): col=l15=qrow, k=l4*8+j = d (padded 80->96)
    bf16x8 qf[3];
    {
        const short* qp = qkv + (size_t)(q0 + l15) * QKVN + h*HDIM;
        qf[0] = *reinterpret_cast<const bf16x8*>(qp + l4*8);
        qf[1] = *reinterpret_cast<const bf16x8*>(qp + 32 + l4*8);
        qf[2] = (l4 < 2) ? *reinterpret_cast<const bf16x8*>(qp + 64 + l4*8) : bzero;
    }

    // per-lane softmax state (exp2 domain, scaled), q-row = q0 + l15
    float m = -3.4e38f, lsum = 0.f;
    f32x4 O[5];   // O^T: lane holds d = dt*16 + 4*l4 + r, qrow = l15
    #pragma unroll
    for (int dt = 0; dt < 5; ++dt) O[dt] = (f32x4){0.f,0.f,0.f,0.f};

    // ---- K staging geometry ----
    int kkey[3], ku[3];
    const short* kptr[3];
    short* klds[3];
    #pragma unroll
    for (int i = 0; i < 3; ++i) {
        int task = tid + i*256;
        kkey[i] = task / 12;
        ku[i]   = task - kkey[i]*12;
        kptr[i] = qkv + (size_t)(s0 + kkey[i])*QKVN + EMB + h*HDIM + ku[i]*8;
        klds[i] = &Kl[kkey[i]][(ku[i] ^ (kkey[i] & 7))*8];
    }

    // ---- V staging geometry (uniform): key k=l, d in [20w, 20w+20) ----
    const int vu  = ((l >> 2) & 3) | ((l >> 5) << 2);   // unit 0..7
    const int vbs = ((l >> 4) & 1) * 4 + (l & 3);       // pos  0..7
    const int vd0 = w * 20;
    const short* vp1 = qkv + (size_t)(s0 + l) * QKVN + 2*EMB + h*HDIM + vd0;

    // ---- preload chunk 0 ----
    bf16x8 kreg[3];
    bf16x8 vA, vB;
    bf16x4 vC;
    #pragma unroll
    for (int i = 0; i < 3; ++i)
        kreg[i] = (ku[i] < 10) ? *reinterpret_cast<const bf16x8*>(kptr[i]) : bzero;
    vA = *reinterpret_cast<const bf16x8*>(vp1);
    vB = *reinterpret_cast<const bf16x8*>(vp1 + 8);
    vC = *reinterpret_cast<const bf16x4*>(vp1 + 16);

    const float scale2 = 0.1612982054f;   // log2(e)/sqrt(80)
    const int nk = s1 - s0;
    const size_t step = (size_t)64 * QKVN;
    short* vt_flat = &Vt[0][0];

    for (int kc = 0; kc < nk; kc += 64) {
        __syncthreads();   // previous chunk's LDS reads complete

        // ---- write staged registers to LDS ----
        #pragma unroll
        for (int i = 0; i < 3; ++i)
            *reinterpret_cast<bf16x8*>(klds[i]) = kreg[i];
        #pragma unroll
        for (int e = 0; e < 8; ++e) {
            int d = vd0 + e;
            vt_flat[d*64 + ((vu ^ (d & 7)) & 7)*8 + vbs] = vA[e];
        }
        #pragma unroll
        for (int e = 0; e < 8; ++e) {
            int d = vd0 + 8 + e;
            vt_flat[d*64 + ((vu ^ (d & 7)) & 7)*8 + vbs] = vB[e];
        }
        #pragma unroll
        for (int e = 0; e < 4; ++e) {
            int d = vd0 + 16 + e;
            vt_flat[d*64 + ((vu ^ (d & 7)) & 7)*8 + vbs] = vC[e];
        }

        // ---- issue next chunk's global loads (overlap with compute) ----
        if (kc + 64 < nk) {
            #pragma unroll
            for (int i = 0; i < 3; ++i) {
                kptr[i] += step;
                if (ku[i] < 10) kreg[i] = *reinterpret_cast<const bf16x8*>(kptr[i]);
            }
            vp1 += step;
            vA = *reinterpret_cast<const bf16x8*>(vp1);
            vB = *reinterpret_cast<const bf16x8*>(vp1 + 8);
            vC = *reinterpret_cast<const bf16x4*>(vp1 + 16);
        }
        __syncthreads();   // staged LDS visible to all waves

        // ---- S^T = K Q : 4 key-tiles x 3 k-steps (swapped operands) ----
        f32x4 S[4];
        __builtin_amdgcn_s_setprio(1);
        #pragma unroll
        for (int ct = 0; ct < 4; ++ct) {
            f32x4 acc = (f32x4){0.f,0.f,0.f,0.f};
            int key = ct*16 + l15;
            #pragma unroll
            for (int t = 0; t < 3; ++t) {
                int u = (4*t + l4) ^ (key & 7);
                bf16x8 a = *reinterpret_cast<const bf16x8*>(&Kl[key][u*8]);
                acc = __builtin_amdgcn_mfma_f32_16x16x32_bf16(a, qf[t], acc, 0, 0, 0);
            }
            S[ct] = acc;   // S[ct][r] = S^T[key=16ct+4*l4+r][qrow=l15]
        }
        __builtin_amdgcn_s_setprio(0);

        // ---- per-lane online softmax over 64 keys (max on raw S) ----
        float mxr = -3.4e38f;
        #pragma unroll
        for (int ct = 0; ct < 4; ++ct)
            #pragma unroll
            for (int r = 0; r < 4; ++r) mxr = fmaxf(mxr, S[ct][r]);
        float mx = mxr * scale2;
        mx = fmaxf(mx, __shfl_xor(mx, 16));
        mx = fmaxf(mx, __shfl_xor(mx, 32));
        // T13 defer-rescale: skip O-rescale when bounded (P <= 2^8, f32 acc)
        if (!__all(mx - m <= 8.f)) {
            float mn   = fmaxf(m, mx);
            float corr = exp2f(m - mn);
            lsum *= corr;
            #pragma unroll
            for (int dt = 0; dt < 5; ++dt)
                #pragma unroll
                for (int r = 0; r < 4; ++r) O[dt][r] *= corr;
            m = mn;
        }
        float p[4][4];
        float ps = 0.f;
        #pragma unroll
        for (int ct = 0; ct < 4; ++ct)
            #pragma unroll
            for (int r = 0; r < 4; ++r) {
                float e = exp2f(fmaf(S[ct][r], scale2, -m));
                p[ct][r] = e;
                ps += e;
            }
        ps += __shfl_xor(ps, 16);
        ps += __shfl_xor(ps, 32);
        lsum += ps;

        // ---- O^T += V^T P^T : per s-half one b128 A-frag read per d-tile ----
        #pragma unroll
        for (int s2 = 0; s2 < 2; ++s2) {
            bf16x8 pb;
            #pragma unroll
            for (int j = 0; j < 8; ++j)
                pb[j] = f2bf(p[2*s2 + (j>>2)][j & 3]);
            __builtin_amdgcn_s_setprio(1);
            #pragma unroll
            for (int dt = 0; dt < 5; ++dt) {
                int d = dt*16 + l15;
                bf16x8 va = *reinterpret_cast<const bf16x8*>(
                    &vt_flat[d*64 + (((4*s2 + l4) ^ (d & 7)) & 7)*8]);
                O[dt] = __builtin_amdgcn_mfma_f32_16x16x32_bf16(va, pb, O[dt], 0, 0, 0);
            }
            __builtin_amdgcn_s_setprio(0);
        }
    }

    // ---- normalize (per-lane scalar), write O^T as packed 8 B stores ----
    float inv = 1.f / lsum;
    short* orow = aout + (size_t)(q0 + l15) * EMB + h*HDIM;
    #pragma unroll
    for (int dt = 0; dt < 5; ++dt) {
        bf16x4 o4;
        #pragma unroll
        for (int r = 0; r < 4; ++r) o4[r] = f2bf(O[dt][r] * inv);
        *reinterpret_cast<bf16x4*>(&orow[dt*16 + 4*l4]) = o4;
    }
}

// ---------------------------------------------------------------------------
extern "C" void kernel_launch(void* const* d_in, const int* in_sizes, int n_in,
                              void* d_out, int out_size, void* d_ws, size_t ws_size,
                              hipStream_t stream)
{
    const float* x      = (const float*)d_in[0];
    const float* rpe    = (const float*)d_in[1];
    const float* qkv_w  = (const float*)d_in[2];
    const float* qkv_b  = (const float*)d_in[3];
    const float* proj_w = (const float*)d_in[4];
    const float* proj_b = (const float*)d_in[5];
    const int*   cu     = (const int*)d_in[6];
    float* out = (float*)d_out;

    short* ws       = (short*)d_ws;
    short* qkv_bf   = ws;                                   // SEQ*QKVN
    short* x_bf     = qkv_bf  + (size_t)SEQ * QKVN;         // SEQ*EMB
    short* qkvw_bf  = x_bf    + (size_t)SEQ * EMB;          // QKVN*EMB
    short* projw_bf = qkvw_bf + (size_t)QKVN * EMB;         // EMB*EMB
    short* attn_bf  = projw_bf+ (size_t)EMB * EMB;          // SEQ*EMB

    dim3 blk(256);

    // 0) convert all three inputs to bf16 in one launch
    const int na8 = SEQ*EMB/8, nb8 = QKVN*EMB/8, nc8 = EMB*EMB/8;
    cvt3_kernel<<<dim3((na8+nb8+nc8)/256), blk, 0, stream>>>(
        x, x_bf, na8, qkv_w, qkvw_bf, nb8, proj_w, projw_bf, nc8);

    // 1) qkv = x @ qkv_w^T + qkv_b  (bf16 out; 128x128 tile, XCD-swizzled
    //    1-D grid, 2-phase double-buffered K-loop)
    gemm_bf16_nt<short, true><<<dim3((QKVN/128)*(SEQ/128)), blk, 0, stream>>>(
        x_bf, EMB, qkvw_bf, qkv_b, qkv_bf, SEQ, QKVN, EMB);

    // 2) RoPE in-place on bf16 q,k
    rope_bf16_kernel<<<dim3(2*SEQ*NHEAD*5/256), blk, 0, stream>>>(qkv_bf, rpe);

    // 3) block-diagonal MFMA attention -> bf16 planar attn_bf (1-D XCD grid)
    attn_mfma<<<dim3(16*NSEGS*NHEAD), blk, 0, stream>>>(qkv_bf, cu, attn_bf);

    // 4) out = attn @ proj_w^T + proj_b (f32 out, 128x64 tile, dbuf,
    //    XCD-swizzled 1-D grid: 480 blocks = 8 XCDs x (20 cols x 3 rows))
    gemm_bf16_nt64<float, true><<<dim3((EMB/64)*(SEQ/128)), blk, 0, stream>>>(
        attn_bf, EMB, projw_bf, proj_b, out, SEQ, EMB, EMB);
}

// Round 19
// 127.501 us; speedup vs baseline: 1.0337x; 1.0027x over previous
//
#include <hip/hip_runtime.h>
#include <hip/hip_bf16.h>
#include <math.h>

// Problem constants (fixed by reference)
#define SEQ   3072
#define EMB   1280
#define NHEAD 16
#define HDIM  80
#define QKVN  3840   // 3*EMB
#define NSEGS 3

typedef __attribute__((ext_vector_type(8))) short bf16x8;  // 8 bf16 (4 VGPRs)
typedef __attribute__((ext_vector_type(4))) short bf16x4;  // 4 bf16 (8 B)
typedef __attribute__((ext_vector_type(4))) float f32x4;   // MFMA C/D frag

__device__ __forceinline__ short f2bf(float f) {
    __hip_bfloat16 h = __float2bfloat16(f);
    return *reinterpret_cast<short*>(&h);
}
__device__ __forceinline__ float bf2f(short s) {
    unsigned int u = ((unsigned int)(unsigned short)s) << 16;
    union { unsigned int u; float f; } c; c.u = u;
    return c.f;
}

// async global->LDS, 16 B per lane; LDS dest = wave-uniform base + lane*16
__device__ __forceinline__ void gload_lds16(const void* g, void* l) {
    __builtin_amdgcn_global_load_lds(
        (const __attribute__((address_space(1))) unsigned int*)g,
        (__attribute__((address_space(3))) unsigned int*)l, 16, 0, 0);
}

// ---------------------------------------------------------------------------
// f32 -> bf16 conversion for all three inputs in ONE launch (8 elems/thread)
// ---------------------------------------------------------------------------
__global__ __launch_bounds__(256)
void cvt3_kernel(const float* __restrict__ a, short* __restrict__ oa, int na8,
                 const float* __restrict__ b, short* __restrict__ ob, int nb8,
                 const float* __restrict__ c, short* __restrict__ oc, int nc8)
{
    int j = blockIdx.x * 256 + threadIdx.x;
    const float* src; short* dst;
    if (j < na8) { src = a; dst = oa; }
    else if ((j -= na8) < nb8) { src = b; dst = ob; }
    else { j -= nb8; src = c; dst = oc; }
    float4 x = *reinterpret_cast<const float4*>(&src[j*8]);
    float4 y = *reinterpret_cast<const float4*>(&src[j*8+4]);
    bf16x8 o;
    o[0]=f2bf(x.x); o[1]=f2bf(x.y); o[2]=f2bf(x.z); o[3]=f2bf(x.w);
    o[4]=f2bf(y.x); o[5]=f2bf(y.y); o[6]=f2bf(y.z); o[7]=f2bf(y.w);
    *reinterpret_cast<bf16x8*>(&dst[j*8]) = o;
}

// ---------------------------------------------------------------------------
// bf16 MFMA GEMM, 128x128 tile, BK=32, 2-phase double-buffer (verified r16).
// SWZ: XCD-aware 1-D grid decode (verified round 15; bijective, rows=8*3).
// ---------------------------------------------------------------------------
__device__ __forceinline__ void store_val(float v, float* p) { *p = v; }
__device__ __forceinline__ void store_val(float v, short* p) { *p = f2bf(v); }

template<typename OT, bool SWZ>
__global__ __launch_bounds__(256)
void gemm_bf16_nt(const short* __restrict__ A, int lda,
                  const short* __restrict__ B,
                  const float* __restrict__ bias, OT* __restrict__ C,
                  int M, int N, int K)
{
    __shared__ short As0[128][32], Bs0[128][32];   // buffer 0 (16 KB)
    __shared__ short As1[128][32], Bs1[128][32];   // buffer 1 (16 KB)

    int bx, by;
    if (SWZ) {
        const int flat = blockIdx.x;
        const int xcd  = flat & 7;
        const int i    = flat >> 3;
        by = xcd * 3 + (i % 3);
        bx = i / 3;
    } else {
        bx = blockIdx.x;
        by = blockIdx.y;
    }

    const int tid = threadIdx.x;
    const int w   = tid >> 6;
    const int l   = tid & 63;
    const int l15 = l & 15;
    const int l4  = l >> 4;
    const int wr  = w >> 1;
    const int wc  = w & 1;
    const int row0 = by * 128;
    const int col0 = bx * 128;

    const int srow = l >> 2;
    const int sk   = (l & 3) * 8;
    const int c0 = w, c1 = w + 4;

    f32x4 acc[4][4];
    #pragma unroll
    for (int mi = 0; mi < 4; ++mi)
        #pragma unroll
        for (int ni = 0; ni < 4; ++ni) acc[mi][ni] = (f32x4){0.f,0.f,0.f,0.f};

#define STAGE_NT(AS, BS, KOFF)                                                          \
    do {                                                                                \
        gload_lds16(&A[(size_t)(row0 + c0*16 + srow) * lda + (KOFF) + sk], &AS[c0*16][0]); \
        gload_lds16(&A[(size_t)(row0 + c1*16 + srow) * lda + (KOFF) + sk], &AS[c1*16][0]); \
        gload_lds16(&B[(size_t)(col0 + c0*16 + srow) * K   + (KOFF) + sk], &BS[c0*16][0]); \
        gload_lds16(&B[(size_t)(col0 + c1*16 + srow) * K   + (KOFF) + sk], &BS[c1*16][0]); \
    } while (0)

#define COMPUTE_NT(AS, BS)                                                              \
    do {                                                                                \
        bf16x8 af[4], bfr[4];                                                           \
        _Pragma("unroll")                                                               \
        for (int mi = 0; mi < 4; ++mi)                                                  \
            af[mi] = *reinterpret_cast<const bf16x8*>(&AS[wr*64 + mi*16 + l15][l4*8]);  \
        _Pragma("unroll")                                                               \
        for (int ni = 0; ni < 4; ++ni)                                                  \
            bfr[ni] = *reinterpret_cast<const bf16x8*>(&BS[wc*64 + ni*16 + l15][l4*8]); \
        _Pragma("unroll")                                                               \
        for (int mi = 0; mi < 4; ++mi)                                                  \
            _Pragma("unroll")                                                           \
            for (int ni = 0; ni < 4; ++ni)                                              \
                acc[mi][ni] = __builtin_amdgcn_mfma_f32_16x16x32_bf16(                  \
                    af[mi], bfr[ni], acc[mi][ni], 0, 0, 0);                             \
    } while (0)

    STAGE_NT(As0, Bs0, 0);
    __syncthreads();

    for (int k0 = 0; k0 < K; k0 += 64) {
        if (k0 + 32 < K) STAGE_NT(As1, Bs1, k0 + 32);
        COMPUTE_NT(As0, Bs0);
        __syncthreads();
        if (k0 + 64 < K) STAGE_NT(As0, Bs0, k0 + 64);
        COMPUTE_NT(As1, Bs1);
        __syncthreads();
    }
#undef STAGE_NT
#undef COMPUTE_NT

    #pragma unroll
    for (int ni = 0; ni < 4; ++ni) {
        int col = col0 + wc*64 + ni*16 + l15;
        float bv = bias[col];
        #pragma unroll
        for (int mi = 0; mi < 4; ++mi) {
            #pragma unroll
            for (int r = 0; r < 4; ++r) {
                size_t row = (size_t)(row0 + wr*64 + mi*16 + l4*4 + r);
                store_val(acc[mi][ni][r] + bv, &C[row * (size_t)N + col]);
            }
        }
    }
}

// ---------------------------------------------------------------------------
// bf16 MFMA GEMM, 128x64 tile, BK=32, 2-phase double-buffer — proj GEMM.
// SWZ: XCD-aware 1-D decode (480 blocks = 8 XCDs x 20 cols x 3 rows).
// ---------------------------------------------------------------------------
template<typename OT, bool SWZ>
__global__ __launch_bounds__(256)
void gemm_bf16_nt64(const short* __restrict__ A, int lda,
                    const short* __restrict__ B,
                    const float* __restrict__ bias, OT* __restrict__ C,
                    int M, int N, int K)
{
    __shared__ short As0[128][32], Bs0[64][32];   // buffer 0 (12 KB)
    __shared__ short As1[128][32], Bs1[64][32];   // buffer 1 (12 KB)

    int bx, by;
    if (SWZ) {
        const int flat = blockIdx.x;
        const int xcd  = flat & 7;
        const int i    = flat >> 3;
        by = xcd * 3 + (i % 3);
        bx = i / 3;
    } else {
        bx = blockIdx.x;
        by = blockIdx.y;
    }

    const int tid = threadIdx.x;
    const int w   = tid >> 6;
    const int l   = tid & 63;
    const int l15 = l & 15;
    const int l4  = l >> 4;
    const int wr  = w >> 1;
    const int wc  = w & 1;
    const int row0 = by * 128;
    const int col0 = bx * 64;

    const int srow = l >> 2;
    const int sk   = (l & 3) * 8;
    const int c0 = w, c1 = w + 4;

    f32x4 acc[4][2];
    #pragma unroll
    for (int mi = 0; mi < 4; ++mi)
        #pragma unroll
        for (int ni = 0; ni < 2; ++ni) acc[mi][ni] = (f32x4){0.f,0.f,0.f,0.f};

#define STAGE_NT64(AS, BS, KOFF)                                                        \
    do {                                                                                \
        gload_lds16(&A[(size_t)(row0 + c0*16 + srow) * lda + (KOFF) + sk], &AS[c0*16][0]); \
        gload_lds16(&A[(size_t)(row0 + c1*16 + srow) * lda + (KOFF) + sk], &AS[c1*16][0]); \
        gload_lds16(&B[(size_t)(col0 + w*16  + srow) * K   + (KOFF) + sk], &BS[w*16][0]);  \
    } while (0)

#define COMPUTE_NT64(AS, BS)                                                            \
    do {                                                                                \
        bf16x8 af[4], bfr[2];                                                           \
        _Pragma("unroll")                                                               \
        for (int mi = 0; mi < 4; ++mi)                                                  \
            af[mi] = *reinterpret_cast<const bf16x8*>(&AS[wr*64 + mi*16 + l15][l4*8]);  \
        _Pragma("unroll")                                                               \
        for (int ni = 0; ni < 2; ++ni)                                                  \
            bfr[ni] = *reinterpret_cast<const bf16x8*>(&BS[wc*32 + ni*16 + l15][l4*8]); \
        _Pragma("unroll")                                                               \
        for (int mi = 0; mi < 4; ++mi)                                                  \
            _Pragma("unroll")                                                           \
            for (int ni = 0; ni < 2; ++ni)                                              \
                acc[mi][ni] = __builtin_amdgcn_mfma_f32_16x16x32_bf16(                  \
                    af[mi], bfr[ni], acc[mi][ni], 0, 0, 0);                             \
    } while (0)

    STAGE_NT64(As0, Bs0, 0);
    __syncthreads();

    for (int k0 = 0; k0 < K; k0 += 64) {
        if (k0 + 32 < K) STAGE_NT64(As1, Bs1, k0 + 32);
        COMPUTE_NT64(As0, Bs0);
        __syncthreads();
        if (k0 + 64 < K) STAGE_NT64(As0, Bs0, k0 + 64);
        COMPUTE_NT64(As1, Bs1);
        __syncthreads();
    }
#undef STAGE_NT64
#undef COMPUTE_NT64

    #pragma unroll
    for (int ni = 0; ni < 2; ++ni) {
        int col = col0 + wc*32 + ni*16 + l15;
        float bv = bias[col];
        #pragma unroll
        for (int mi = 0; mi < 4; ++mi) {
            #pragma unroll
            for (int r = 0; r < 4; ++r) {
                size_t row = (size_t)(row0 + wr*64 + mi*16 + l4*4 + r);
                store_val(acc[mi][ni][r] + bv, &C[row * (size_t)N + col]);
            }
        }
    }
}

// ---------------------------------------------------------------------------
// RoPE in-place on bf16 q,k slices (unchanged).
// ---------------------------------------------------------------------------
__global__ __launch_bounds__(256)
void rope_bf16_kernel(short* __restrict__ qkv, const float* __restrict__ rpe)
{
    int idx = blockIdx.x * 256 + threadIdx.x;
    int blk = idx % 5;
    int h   = (idx / 5) % NHEAD;
    int s   = (idx / (5*NHEAD)) % SEQ;
    int t   = idx / (5*NHEAD*SEQ);
    int d0  = blk * 8;

    const float* rp = rpe + s*40 + d0;
    short* p = qkv + (size_t)s*QKVN + t*EMB + h*HDIM + d0;
    bf16x8 v0 = *reinterpret_cast<const bf16x8*>(p);
    bf16x8 v1 = *reinterpret_cast<const bf16x8*>(p + 40);
    bf16x8 o0, o1;
    #pragma unroll
    for (int j = 0; j < 8; ++j) {
        float ang = rp[j];
        float sn = sinf(ang), cs = cosf(ang);
        float a = bf2f(v0[j]), b = bf2f(v1[j]);
        o0[j] = f2bf(a*cs - b*sn);
        o1[j] = f2bf(b*cs + a*sn);
    }
    *reinterpret_cast<bf16x8*>(p)      = o0;
    *reinterpret_cast<bf16x8*>(p + 40) = o1;
}

// ---------------------------------------------------------------------------
// MFMA flash attention — round 16 verified structure + round 19 reorders:
//  (a) K pad-units (10,11) written ONCE in prologue (constant zeros);
//      in-loop staging only writes real units -> fewer ds_writes per chunk.
//  (b) lsum shuffle-reduce deferred until AFTER the PV MFMAs (ps not needed
//      by PV) -> shuffles hide under MFMA latency.
//  (c) redundant &7 masks dropped in PV addresses (operands already < 8).
// ---------------------------------------------------------------------------
__global__ __launch_bounds__(256, 4)
void attn_mfma(const short* __restrict__ qkv, const int* __restrict__ cu,
               short* __restrict__ aout)
{
    const int flat = blockIdx.x;
    const int xcd  = flat & 7;
    const int rem  = flat >> 3;
    const int qt   = rem & 15;
    const int shhi = rem >> 4;
    const int sh   = xcd + 8*shhi;    // 0..47
    const int h    = sh / 3;
    const int seg  = sh - 3*h;
    const int s0 = cu[seg], s1 = cu[seg+1];

    const int tid = threadIdx.x;
    const int w   = tid >> 6;
    const int l   = tid & 63;
    const int l15 = l & 15;
    const int l4  = l >> 4;

    __shared__ short Kl[64][128];    // 16 KB: K rows, XOR-swizzled 8-elem units
    __shared__ short Vt[HDIM][64];   // 10 KB: V^T, quad-permuted + swizzled

    const int q0 = s0 + qt*64 + w*16;

    bf16x8 bzero;
    #pragma unroll
    for (int j = 0; j < 8; ++j) bzero[j] = 0;

    // Q fragments (B-operand): col=l15=qrow, k=l4*8+j = d (padded 80->96)
    bf16x8 qf[3];
    {
        const short* qp = qkv + (size_t)(q0 + l15) * QKVN + h*HDIM;
        qf[0] = *reinterpret_cast<const bf16x8*>(qp + l4*8);
        qf[1] = *reinterpret_cast<const bf16x8*>(qp + 32 + l4*8);
        qf[2] = (l4 < 2) ? *reinterpret_cast<const bf16x8*>(qp + 64 + l4*8) : bzero;
    }

    // per-lane softmax state (exp2 domain, scaled), q-row = q0 + l15
    float m = -3.4e38f, lsum = 0.f;
    f32x4 O[5];   // O^T: lane holds d = dt*16 + 4*l4 + r, qrow = l15
    #pragma unroll
    for (int dt = 0; dt < 5; ++dt) O[dt] = (f32x4){0.f,0.f,0.f,0.f};

    // ---- K staging geometry ----
    int kkey[3], ku[3];
    const short* kptr[3];
    short* klds[3];
    #pragma unroll
    for (int i = 0; i < 3; ++i) {
        int task = tid + i*256;
        kkey[i] = task / 12;
        ku[i]   = task - kkey[i]*12;
        kptr[i] = qkv + (size_t)(s0 + kkey[i])*QKVN + EMB + h*HDIM + ku[i]*8;
        klds[i] = &Kl[kkey[i]][(ku[i] ^ (kkey[i] & 7))*8];
    }

    // ---- write constant zero pad-units (10,11) ONCE ----
    #pragma unroll
    for (int i = 0; i < 3; ++i)
        if (ku[i] >= 10) *reinterpret_cast<bf16x8*>(klds[i]) = bzero;

    // ---- V staging geometry (uniform): key k=l, d in [20w, 20w+20) ----
    const int vu  = ((l >> 2) & 3) | ((l >> 5) << 2);   // unit 0..7
    const int vbs = ((l >> 4) & 1) * 4 + (l & 3);       // pos  0..7
    const int vd0 = w * 20;
    const short* vp1 = qkv + (size_t)(s0 + l) * QKVN + 2*EMB + h*HDIM + vd0;

    // ---- preload chunk 0 ----
    bf16x8 kreg[3];
    bf16x8 vA, vB;
    bf16x4 vC;
    #pragma unroll
    for (int i = 0; i < 3; ++i)
        kreg[i] = (ku[i] < 10) ? *reinterpret_cast<const bf16x8*>(kptr[i]) : bzero;
    vA = *reinterpret_cast<const bf16x8*>(vp1);
    vB = *reinterpret_cast<const bf16x8*>(vp1 + 8);
    vC = *reinterpret_cast<const bf16x4*>(vp1 + 16);

    const float scale2 = 0.1612982054f;   // log2(e)/sqrt(80)
    const int nk = s1 - s0;
    const size_t step = (size_t)64 * QKVN;
    short* vt_flat = &Vt[0][0];

    for (int kc = 0; kc < nk; kc += 64) {
        __syncthreads();   // previous chunk's LDS reads complete

        // ---- write staged registers to LDS (real units only) ----
        #pragma unroll
        for (int i = 0; i < 3; ++i)
            if (ku[i] < 10) *reinterpret_cast<bf16x8*>(klds[i]) = kreg[i];
        #pragma unroll
        for (int e = 0; e < 8; ++e) {
            int d = vd0 + e;
            vt_flat[d*64 + ((vu ^ (d & 7)) & 7)*8 + vbs] = vA[e];
        }
        #pragma unroll
        for (int e = 0; e < 8; ++e) {
            int d = vd0 + 8 + e;
            vt_flat[d*64 + ((vu ^ (d & 7)) & 7)*8 + vbs] = vB[e];
        }
        #pragma unroll
        for (int e = 0; e < 4; ++e) {
            int d = vd0 + 16 + e;
            vt_flat[d*64 + ((vu ^ (d & 7)) & 7)*8 + vbs] = vC[e];
        }

        // ---- issue next chunk's global loads (overlap with compute) ----
        if (kc + 64 < nk) {
            #pragma unroll
            for (int i = 0; i < 3; ++i) {
                kptr[i] += step;
                if (ku[i] < 10) kreg[i] = *reinterpret_cast<const bf16x8*>(kptr[i]);
            }
            vp1 += step;
            vA = *reinterpret_cast<const bf16x8*>(vp1);
            vB = *reinterpret_cast<const bf16x8*>(vp1 + 8);
            vC = *reinterpret_cast<const bf16x4*>(vp1 + 16);
        }
        __syncthreads();   // staged LDS visible to all waves

        // ---- S^T = K Q : 4 key-tiles x 3 k-steps (swapped operands) ----
        f32x4 S[4];
        __builtin_amdgcn_s_setprio(1);
        #pragma unroll
        for (int ct = 0; ct < 4; ++ct) {
            f32x4 acc = (f32x4){0.f,0.f,0.f,0.f};
            int key = ct*16 + l15;
            #pragma unroll
            for (int t = 0; t < 3; ++t) {
                int u = (4*t + l4) ^ (key & 7);
                bf16x8 a = *reinterpret_cast<const bf16x8*>(&Kl[key][u*8]);
                acc = __builtin_amdgcn_mfma_f32_16x16x32_bf16(a, qf[t], acc, 0, 0, 0);
            }
            S[ct] = acc;   // S[ct][r] = S^T[key=16ct+4*l4+r][qrow=l15]
        }
        __builtin_amdgcn_s_setprio(0);

        // ---- per-lane online softmax over 64 keys (max on raw S) ----
        float mxr = -3.4e38f;
        #pragma unroll
        for (int ct = 0; ct < 4; ++ct)
            #pragma unroll
            for (int r = 0; r < 4; ++r) mxr = fmaxf(mxr, S[ct][r]);
        float mx = mxr * scale2;
        mx = fmaxf(mx, __shfl_xor(mx, 16));
        mx = fmaxf(mx, __shfl_xor(mx, 32));
        // T13 defer-rescale: skip O-rescale when bounded (P <= 2^8, f32 acc)
        if (!__all(mx - m <= 8.f)) {
            float mn   = fmaxf(m, mx);
            float corr = exp2f(m - mn);
            lsum *= corr;
            #pragma unroll
            for (int dt = 0; dt < 5; ++dt)
                #pragma unroll
                for (int r = 0; r < 4; ++r) O[dt][r] *= corr;
            m = mn;
        }
        float p[4][4];
        float ps = 0.f;
        #pragma unroll
        for (int ct = 0; ct < 4; ++ct)
            #pragma unroll
            for (int r = 0; r < 4; ++r) {
                float e = exp2f(fmaf(S[ct][r], scale2, -m));
                p[ct][r] = e;
                ps += e;
            }

        // ---- O^T += V^T P^T : per s-half one b128 A-frag read per d-tile ----
        #pragma unroll
        for (int s2 = 0; s2 < 2; ++s2) {
            bf16x8 pb;
            #pragma unroll
            for (int j = 0; j < 8; ++j)
                pb[j] = f2bf(p[2*s2 + (j>>2)][j & 3]);
            __builtin_amdgcn_s_setprio(1);
            #pragma unroll
            for (int dt = 0; dt < 5; ++dt) {
                int d = dt*16 + l15;
                bf16x8 va = *reinterpret_cast<const bf16x8*>(
                    &vt_flat[d*64 + (((4*s2 + l4) ^ (d & 7)))*8]);
                O[dt] = __builtin_amdgcn_mfma_f32_16x16x32_bf16(va, pb, O[dt], 0, 0, 0);
            }
            __builtin_amdgcn_s_setprio(0);
        }

        // ---- deferred lsum reduce (hides under PV MFMA latency) ----
        ps += __shfl_xor(ps, 16);
        ps += __shfl_xor(ps, 32);
        lsum += ps;
    }

    // ---- normalize (per-lane scalar), write O^T as packed 8 B stores ----
    float inv = 1.f / lsum;
    short* orow = aout + (size_t)(q0 + l15) * EMB + h*HDIM;
    #pragma unroll
    for (int dt = 0; dt < 5; ++dt) {
        bf16x4 o4;
        #pragma unroll
        for (int r = 0; r < 4; ++r) o4[r] = f2bf(O[dt][r] * inv);
        *reinterpret_cast<bf16x4*>(&orow[dt*16 + 4*l4]) = o4;
    }
}

// ---------------------------------------------------------------------------
extern "C" void kernel_launch(void* const* d_in, const int* in_sizes, int n_in,
                              void* d_out, int out_size, void* d_ws, size_t ws_size,
                              hipStream_t stream)
{
    const float* x      = (const float*)d_in[0];
    const float* rpe    = (const float*)d_in[1];
    const float* qkv_w  = (const float*)d_in[2];
    const float* qkv_b  = (const float*)d_in[3];
    const float* proj_w = (const float*)d_in[4];
    const float* proj_b = (const float*)d_in[5];
    const int*   cu     = (const int*)d_in[6];
    float* out = (float*)d_out;

    short* ws       = (short*)d_ws;
    short* qkv_bf   = ws;                                   // SEQ*QKVN
    short* x_bf     = qkv_bf  + (size_t)SEQ * QKVN;         // SEQ*EMB
    short* qkvw_bf  = x_bf    + (size_t)SEQ * EMB;          // QKVN*EMB
    short* projw_bf = qkvw_bf + (size_t)QKVN * EMB;         // EMB*EMB
    short* attn_bf  = projw_bf+ (size_t)EMB * EMB;          // SEQ*EMB

    dim3 blk(256);

    // 0) convert all three inputs to bf16 in one launch
    const int na8 = SEQ*EMB/8, nb8 = QKVN*EMB/8, nc8 = EMB*EMB/8;
    cvt3_kernel<<<dim3((na8+nb8+nc8)/256), blk, 0, stream>>>(
        x, x_bf, na8, qkv_w, qkvw_bf, nb8, proj_w, projw_bf, nc8);

    // 1) qkv = x @ qkv_w^T + qkv_b  (bf16 out; 128x128 tile, XCD-swizzled
    //    1-D grid, 2-phase double-buffered K-loop)
    gemm_bf16_nt<short, true><<<dim3((QKVN/128)*(SEQ/128)), blk, 0, stream>>>(
        x_bf, EMB, qkvw_bf, qkv_b, qkv_bf, SEQ, QKVN, EMB);

    // 2) RoPE in-place on bf16 q,k
    rope_bf16_kernel<<<dim3(2*SEQ*NHEAD*5/256), blk, 0, stream>>>(qkv_bf, rpe);

    // 3) block-diagonal MFMA attention -> bf16 planar attn_bf (1-D XCD grid)
    attn_mfma<<<dim3(16*NSEGS*NHEAD), blk, 0, stream>>>(qkv_bf, cu, attn_bf);

    // 4) out = attn @ proj_w^T + proj_b (f32 out, 128x64 tile, dbuf,
    //    XCD-swizzled 1-D grid)
    gemm_bf16_nt64<float, true><<<dim3((EMB/64)*(SEQ/128)), blk, 0, stream>>>(
        attn_bf, EMB, projw_bf, proj_b, out, SEQ, EMB, EMB);
}